// Round 15
// baseline (201.464 us; speedup 1.0000x reference)
//
#include <hip/hip_runtime.h>
#include <hip/hip_fp16.h>

#define IN_DIM 128
#define HID 32
#define HEADS 4
#define OUTC (HEADS*HID)   // 128
#define NEG_SLOPE 0.2f
#define BSH 4
#define BN 16              // nodes per bucket
#define BCAP 768           // edges per bucket (mean 512, +11 sigma)
#define NBMAX 3200
#define NCOLS 384          // k(128) | q(128) | v(128)
#define WPB 192            // w_prep blocks (NCOLS*IN_DIM/256)
#define NP 25              // dst partitions (dst>>11)
#define PSH 11
#define PCAP 72704         // records per partition (mean 65536, +28 sigma)
#define PBLK 18            // pass2 chunks per partition (18*4096 >= PCAP)
#define OSTRIDE 392        // padded LDS out row stride (fp16)

typedef _Float16 f16x8 __attribute__((ext_vector_type(8)));
typedef float    f32x4 __attribute__((ext_vector_type(4)));

__device__ __forceinline__ unsigned short f2h(float f) {
    return __half_as_ushort(__float2half_rn(f));
}
__device__ __forceinline__ float2 h2f2(unsigned u) {
    __half2 h = *reinterpret_cast<__half2*>(&u);
    return __half22float2(h);
}
__device__ __forceinline__ float qdot2(const uint2& w, const float4& kd) {
    float2 a = h2f2(w.x);
    float2 b = h2f2(w.y);
    return a.x * kd.x + a.y * kd.y + b.x * kd.z + b.y * kd.w;
}
__device__ __forceinline__ void vacc2(const uint2& w, float e, float4& acc) {
    float2 a = h2f2(w.x);
    float2 b = h2f2(w.y);
    acc.x = fmaf(e, a.x, acc.x);
    acc.y = fmaf(e, a.y, acc.y);
    acc.z = fmaf(e, b.x, acc.z);
    acc.w = fmaf(e, b.y, acc.w);
}

// ---------------------------------------------------------------------------
// K_A: FUSED {w_prep || pass1-partition}. Counters pre-zeroed by memset
// (kernel-boundary fence) — NO in-kernel zeroing (round-14 race fixed).
// Blocks [0, WPB): W transpose to fp16 B^T.
// Blocks [WPB, ...): partition edges by dst>>11 (25 partitions), record
//   src<<16|dst, per-wave LDS histograms (4x32) to cut atomic contention.
// ---------------------------------------------------------------------------
__global__ __launch_bounds__(256) void kA_prep_part(
    const float* __restrict__ Wq, const float* __restrict__ Wk,
    const float* __restrict__ Wv, unsigned short* __restrict__ Wt,
    int* __restrict__ pcount,
    const int* __restrict__ src, const int* __restrict__ dst,
    unsigned* __restrict__ ppairs, int ne)
{
    const int tid = threadIdx.x;

    if ((int)blockIdx.x < WPB) {
        int idx = blockIdx.x * 256 + tid;
        if (idx >= NCOLS * IN_DIM) return;
        int c = idx >> 7, k = idx & 127;
        int sel = c >> 7;              // 0:K 1:Q 2:V
        int cc  = c & 127;
        int head = cc >> 5, dcol = cc & 31;
        const float* W = (sel == 0) ? Wk : (sel == 1) ? Wq : Wv;
        Wt[idx] = f2h(W[(size_t)head * IN_DIM * HID + (size_t)k * HID + dcol]);
        return;
    }

    __shared__ int hist[4 * 32];   // per-wave histograms
    __shared__ int base[4 * 32];
    const int bblk = blockIdx.x - WPB;
    const int wid  = tid >> 6;

    if (tid < 128) hist[tid] = 0;
    __syncthreads();

    const int ne4 = ne >> 2;
    const int4* s4 = (const int4*)src;
    const int4* d4 = (const int4*)dst;

    int4 sv[4], dv[4];
    int loc[16], pk[16];
    bool val[4];
#pragma unroll
    for (int k2 = 0; k2 < 4; ++k2) {
        int idx = bblk * 1024 + k2 * 256 + tid;
        val[k2] = idx < ne4;
        if (val[k2]) { sv[k2] = s4[idx]; dv[k2] = d4[idx]; }
        else { sv[k2] = make_int4(0,0,0,0); dv[k2] = make_int4(0,0,0,0); }
    }
#pragma unroll
    for (int k2 = 0; k2 < 4; ++k2) {
        int dd[4] = { dv[k2].x, dv[k2].y, dv[k2].z, dv[k2].w };
#pragma unroll
        for (int j = 0; j < 4; ++j) {
            int p = dd[j] >> PSH;
            pk[k2*4+j]  = p;
            loc[k2*4+j] = val[k2] ? atomicAdd(&hist[wid * 32 + p], 1) : 0;
        }
    }
    __syncthreads();
    if (tid < 128)
        base[tid] = hist[tid] ? atomicAdd(&pcount[tid & 31], hist[tid]) : 0;
    __syncthreads();
#pragma unroll
    for (int k2 = 0; k2 < 4; ++k2) {
        if (!val[k2]) continue;
        int ss[4] = { sv[k2].x, sv[k2].y, sv[k2].z, sv[k2].w };
        int dd[4] = { dv[k2].x, dv[k2].y, dv[k2].z, dv[k2].w };
#pragma unroll
        for (int j = 0; j < 4; ++j) {
            int p   = pk[k2*4+j];
            int pos = base[wid * 32 + p] + loc[k2*4+j];
            if (pos >= 0 && pos < PCAP)
                ppairs[(size_t)p * PCAP + pos] =
                    ((unsigned)ss[j] << 16) | (unsigned)dd[j];
        }
    }
    if (bblk == 0 && tid == 0) {
        for (int e = ne4 * 4; e < ne; ++e) {
            int p   = dst[e] >> PSH;
            int pos = atomicAdd(&pcount[p], 1);
            if (pos >= 0 && pos < PCAP)
                ppairs[(size_t)p * PCAP + pos] =
                    ((unsigned)src[e] << 16) | (unsigned)dst[e];
        }
    }
}

// ---------------------------------------------------------------------------
// K_B: FUSED {pass2 || proj}.
// Blocks [0, NP*PBLK): bin partition chunks into 128 buckets each
//   (pairs record = src<<4 | dst&15; gcount[p*128 + (dst>>4)&127]).
// Blocks [NP*PBLK, ...): MFMA projections -> K, Qa, Va fp16 with LDS-staged
//   vectorized epilogue. pass2 (~8us) hides under proj (~20us).
// ---------------------------------------------------------------------------
__global__ __launch_bounds__(256) void kB_bin_proj(
    const unsigned* __restrict__ ppairs, const int* __restrict__ pcount,
    int* __restrict__ gcount, unsigned* __restrict__ pairs,
    const float* __restrict__ h, const unsigned short* __restrict__ Wt,
    unsigned short* __restrict__ K, unsigned short* __restrict__ Qa,
    unsigned short* __restrict__ Va,
    int p2blk, int n)
{
    __shared__ __align__(16) char smem_raw[32 * OSTRIDE * 2];   // 24.5KB
    const int tid = threadIdx.x;

    if ((int)blockIdx.x < p2blk) {
        // ---------------- pass2: bin into buckets ----------------
        int* hist = (int*)smem_raw;
        int* base = hist + 128;
        const int p = blockIdx.x / PBLK;
        const int c = blockIdx.x % PBLK;

        int mp = pcount[p]; if (mp > PCAP) mp = PCAP;
        const int i0 = c * 4096;
        if (i0 >= mp) return;
        const int iend = min(i0 + 4096, mp);

        if (tid < 128) hist[tid] = 0;
        __syncthreads();

        const unsigned* pp = ppairs + (size_t)p * PCAP;
        unsigned rec[16];
        int loc[16], lb[16];
#pragma unroll
        for (int k = 0; k < 16; ++k) {
            int i = i0 + k * 256 + tid;
            if (i < iend) {
                unsigned r = pp[i];
                rec[k] = r;
                int b = ((r & 0xFFFFu) >> BSH) & 127;
                lb[k]  = b;
                loc[k] = atomicAdd(&hist[b], 1);
            } else {
                rec[k] = 0; lb[k] = -1; loc[k] = 0;
            }
        }
        __syncthreads();
        if (tid < 128)
            base[tid] = hist[tid] ? atomicAdd(&gcount[p * 128 + tid], hist[tid]) : 0;
        __syncthreads();
#pragma unroll
        for (int k = 0; k < 16; ++k) {
            if (lb[k] < 0) continue;
            unsigned r = rec[k];
            int gb  = p * 128 + lb[k];
            int pos = base[lb[k]] + loc[k];
            if (pos < BCAP)
                pairs[(size_t)gb * BCAP + pos] =
                    ((r >> 16) << BSH) | (r & (BN - 1));
        }
        return;
    }

    // ---------------- proj path (MFMA) ----------------
    unsigned short* hsm = (unsigned short*)smem_raw;   // first 8KB: h tile fp16
    const int row0 = (blockIdx.x - p2blk) * 32;

    for (int idx = tid; idx < 32 * 32; idx += 256) {
        int r  = idx >> 5;
        int c4 = idx & 31;            // float4 column
        int gr = row0 + r;
        float4 hv = (gr < n) ? ((const float4*)h)[(size_t)gr * 32 + c4]
                             : make_float4(0.f, 0.f, 0.f, 0.f);
        int sc = (c4 * 4) ^ ((r & 7) << 3);
        __half2 p01 = __floats2half2_rn(hv.x, hv.y);
        __half2 p23 = __floats2half2_rn(hv.z, hv.w);
        uint2 u;
        u.x = *(unsigned*)&p01;
        u.y = *(unsigned*)&p23;
        *(uint2*)&hsm[r * IN_DIM + sc] = u;
    }
    __syncthreads();

    const int w = tid >> 6;
    const int l = tid & 63;
    const int l15 = l & 15;
    const int kg  = l >> 4;
    const _Float16* Wt16 = (const _Float16*)Wt;

    f32x4 acc[2][6];
#pragma unroll
    for (int rt = 0; rt < 2; ++rt)
#pragma unroll
        for (int ct = 0; ct < 6; ++ct) acc[rt][ct] = (f32x4){0.f, 0.f, 0.f, 0.f};

#pragma unroll
    for (int s = 0; s < 4; ++s) {
        int scol = (s * 32 + kg * 8) ^ ((l & 7) << 3);
        f16x8 a0 = *(const f16x8*)&hsm[l15 * IN_DIM + scol];
        f16x8 a1 = *(const f16x8*)&hsm[(l15 + 16) * IN_DIM + scol];
#pragma unroll
        for (int ct = 0; ct < 6; ++ct) {
            int c = w * 96 + ct * 16 + l15;
            f16x8 b = *(const f16x8*)&Wt16[(size_t)c * IN_DIM + s * 32 + kg * 8];
            acc[0][ct] = __builtin_amdgcn_mfma_f32_16x16x32_f16(a0, b, acc[0][ct], 0, 0, 0);
            acc[1][ct] = __builtin_amdgcn_mfma_f32_16x16x32_f16(a1, b, acc[1][ct], 0, 0, 0);
        }
    }
    __syncthreads();   // all hsm reads done; reuse LDS for out staging

    unsigned short* osm = (unsigned short*)smem_raw;   // 32 x OSTRIDE fp16
#pragma unroll
    for (int rt = 0; rt < 2; ++rt) {
#pragma unroll
        for (int ct = 0; ct < 6; ++ct) {
            int cD = w * 96 + ct * 16 + l15;
#pragma unroll
            for (int r = 0; r < 4; ++r) {
                int rowl = rt * 16 + kg * 4 + r;
                osm[rowl * OSTRIDE + cD] = f2h(acc[rt][ct][r]);
            }
        }
    }
    __syncthreads();

    for (int c = tid; c < 32 * 96; c += 256) {
        int row  = c / 96;
        int col4 = c - row * 96;
        int node = row0 + row;
        if (node >= n) continue;
        uint2 v = *(const uint2*)&osm[row * OSTRIDE + col4 * 4];
        int colbase = col4 * 4;
        if (colbase < 128)
            *(uint2*)&K [(size_t)node * OUTC + colbase] = v;
        else if (colbase < 256)
            *(uint2*)&Qa[(size_t)node * OUTC + (colbase - 128)] = v;
        else
            *(uint2*)&Va[(size_t)node * OUTC + (colbase - 256)] = v;
    }
}

// ---------------------------------------------------------------------------
// K_C: bucket gather, two-phase (byte-identical to round 12, verified 110us).
// ---------------------------------------------------------------------------
__global__ __launch_bounds__(256) void gat_bucket(
    const unsigned* __restrict__ pairs, const int* __restrict__ gcount,
    const uint2* __restrict__ Q2, const uint2* __restrict__ V2,
    const ushort4* __restrict__ K4,
    float* __restrict__ out, int n, int nbuck)
{
    __shared__ unsigned short sl[BCAP];
    __shared__ float exls[BCAP * 4];        // per-head ex, 12KB
    __shared__ int cl[BN], cur[BN], off[BN + 1];

    const int b = blockIdx.x;
    if (b >= nbuck) return;
    const int tid = threadIdx.x;

    if (tid < BN) cl[tid] = 0;
    __syncthreads();

    int m = gcount[b]; if (m > BCAP) m = BCAP;
    const unsigned* pb = pairs + (size_t)b * BCAP;

    for (int i = tid; i < m; i += 256) atomicAdd(&cl[pb[i] & (BN - 1)], 1);
    __syncthreads();
    if (tid == 0) {
        int a = 0;
#pragma unroll
        for (int i = 0; i < BN; ++i) { off[i] = a; cur[i] = a; a += cl[i]; }
        off[BN] = a;
    }
    __syncthreads();
    for (int i = tid; i < m; i += 256) {
        unsigned p = pb[i];
        int pos = atomicAdd(&cur[p & (BN - 1)], 1);
        sl[pos] = (unsigned short)(p >> BSH);
    }
    __syncthreads();

    const int gi   = tid >> 5;       // group 0..7 (one node per group per q)
    const int l32  = tid & 31;
    const int hsel = l32 >> 3;       // head 0..3
    const bool wr  = (l32 & 7) == 0; // one writer lane per head

    float dsum[BN / 8];

    // ---- phase A: scores ----
#pragma unroll
    for (int q = 0; q < BN / 8; ++q) {
        int nl   = q * 8 + gi;
        int node = b * BN + nl;
        float ds = 0.f;
        if (node < n) {
            ushort4 kh = K4[(size_t)node * 32 + l32];
            float2 k01 = h2f2(*(unsigned*)&kh.x);
            float2 k23 = h2f2(*(unsigned*)&kh.z);
            const float4 kd = make_float4(k01.x, k01.y, k23.x, k23.y);

            int j        = off[nl];
            const int je = off[nl + 1];
            for (; j + 3 < je; j += 4) {
                int s0 = sl[j], s1 = sl[j + 1], s2 = sl[j + 2], s3 = sl[j + 3];
                uint2 w0 = Q2[(size_t)s0 * 32 + l32];
                uint2 w1 = Q2[(size_t)s1 * 32 + l32];
                uint2 w2 = Q2[(size_t)s2 * 32 + l32];
                uint2 w3 = Q2[(size_t)s3 * 32 + l32];
                float p0 = qdot2(w0, kd), p1 = qdot2(w1, kd);
                float p2 = qdot2(w2, kd), p3 = qdot2(w3, kd);
#pragma unroll
                for (int o = 1; o < 8; o <<= 1) {
                    p0 += __shfl_xor(p0, o, 8);
                    p1 += __shfl_xor(p1, o, 8);
                    p2 += __shfl_xor(p2, o, 8);
                    p3 += __shfl_xor(p3, o, 8);
                }
                float e0 = __expf(p0 > 0.f ? p0 : NEG_SLOPE * p0);
                float e1 = __expf(p1 > 0.f ? p1 : NEG_SLOPE * p1);
                float e2 = __expf(p2 > 0.f ? p2 : NEG_SLOPE * p2);
                float e3 = __expf(p3 > 0.f ? p3 : NEG_SLOPE * p3);
                ds += (e0 + e1) + (e2 + e3);
                if (wr) {
                    exls[(j    ) * 4 + hsel] = e0;
                    exls[(j + 1) * 4 + hsel] = e1;
                    exls[(j + 2) * 4 + hsel] = e2;
                    exls[(j + 3) * 4 + hsel] = e3;
                }
            }
            for (; j < je; ++j) {
                int s0 = sl[j];
                uint2 w0 = Q2[(size_t)s0 * 32 + l32];
                float p0 = qdot2(w0, kd);
#pragma unroll
                for (int o = 1; o < 8; o <<= 1) p0 += __shfl_xor(p0, o, 8);
                float e0 = __expf(p0 > 0.f ? p0 : NEG_SLOPE * p0);
                ds += e0;
                if (wr) exls[j * 4 + hsel] = e0;
            }
        }
        dsum[q] = ds;
    }
    __syncthreads();

    // ---- phase B: values ----
#pragma unroll
    for (int q = 0; q < BN / 8; ++q) {
        int nl   = q * 8 + gi;
        int node = b * BN + nl;
        if (node >= n) continue;

        int j        = off[nl];
        const int je = off[nl + 1];
        float4 acc = make_float4(0.f, 0.f, 0.f, 0.f);

        for (; j + 3 < je; j += 4) {
            int s0 = sl[j], s1 = sl[j + 1], s2 = sl[j + 2], s3 = sl[j + 3];
            uint2 w0 = V2[(size_t)s0 * 32 + l32];
            uint2 w1 = V2[(size_t)s1 * 32 + l32];
            uint2 w2 = V2[(size_t)s2 * 32 + l32];
            uint2 w3 = V2[(size_t)s3 * 32 + l32];
            float e0 = exls[(j    ) * 4 + hsel];
            float e1 = exls[(j + 1) * 4 + hsel];
            float e2 = exls[(j + 2) * 4 + hsel];
            float e3 = exls[(j + 3) * 4 + hsel];
            vacc2(w0, e0, acc); vacc2(w1, e1, acc);
            vacc2(w2, e2, acc); vacc2(w3, e3, acc);
        }
        for (; j < je; ++j) {
            int s0 = sl[j];
            uint2 w0 = V2[(size_t)s0 * 32 + l32];
            float e0 = exls[j * 4 + hsel];
            vacc2(w0, e0, acc);
        }

        float inv = 1.f / fmaxf(dsum[q], 1e-9f);
        float4 o; o.x = acc.x*inv; o.y = acc.y*inv; o.z = acc.z*inv; o.w = acc.w*inv;
        ((float4*)out)[(size_t)node * 32 + l32] = o;
    }
}

extern "C" void kernel_launch(void* const* d_in, const int* in_sizes, int n_in,
                              void* d_out, int out_size, void* d_ws, size_t ws_size,
                              hipStream_t stream) {
    const float* h   = (const float*)d_in[0];
    const int*   src = (const int*)d_in[1];
    const int*   dst = (const int*)d_in[2];
    const float* Wq  = (const float*)d_in[3];
    const float* Wk  = (const float*)d_in[4];
    const float* Wv  = (const float*)d_in[5];
    float* out = (float*)d_out;

    const int n     = in_sizes[0] / IN_DIM;   // 50000
    const int ne    = in_sizes[1];            // 1.6M
    const int nbuck = (n + BN - 1) >> BSH;    // 3125

    // workspace: K|Qa|Va f16 | gcount | pcount | ppairs | pairs | Wt (~56 MB)
    unsigned short* K      = (unsigned short*)d_ws;
    unsigned short* Qa     = K  + (size_t)n * OUTC;
    unsigned short* Va     = Qa + (size_t)n * OUTC;
    int*            gcount = (int*)(Va + (size_t)n * OUTC);
    int*            pcount = gcount + NBMAX;
    unsigned*       ppairs = (unsigned*)(pcount + 64);
    unsigned*       pairs  = ppairs + (size_t)NP * PCAP;
    unsigned short* Wt     = (unsigned short*)(pairs + (size_t)NBMAX * BCAP);

    // zero counters BEFORE kA (kernel boundary = fence; fixes round-14 race)
    hipMemsetAsync(gcount, 0, (NBMAX + 64) * sizeof(int), stream);

    int ne4    = ne >> 2;
    int binblk = (ne4 + 1023) / 1024;         // 391
    kA_prep_part<<<WPB + binblk, 256, 0, stream>>>(
        Wq, Wk, Wv, Wt, pcount, src, dst, ppairs, ne);

    int p2blk   = NP * PBLK;                  // 450
    int projblk = (n + 31) / 32;              // 1563
    kB_bin_proj<<<p2blk + projblk, 256, 0, stream>>>(
        ppairs, pcount, gcount, pairs, h, Wt, K, Qa, Va, p2blk, n);

    gat_bucket<<<nbuck, 256, 0, stream>>>(pairs, gcount, (const uint2*)Qa,
                                          (const uint2*)Va, (const ushort4*)K,
                                          out, n, nbuck);
}

// Round 16
// 164.547 us; speedup vs baseline: 1.2244x; 1.2244x over previous
//
#include <hip/hip_runtime.h>
#include <hip/hip_fp16.h>

#define IN_DIM 128
#define HID 32
#define HEADS 4
#define OUTC (HEADS*HID)   // 128
#define NEG_SLOPE 0.2f
#define BSH 4
#define BN 16              // nodes per bucket
#define BCAP 768           // edges per bucket (mean 512, +11 sigma)
#define NBMAX 3200
#define NCOLS 384          // k(128) | q(128) | v(128)
#define WPB 192            // w_prep blocks (NCOLS*IN_DIM/256)
#define NP 25              // dst partitions (dst>>11)
#define PSH 11
#define PCAP 72704         // records per partition (mean 65536, +28 sigma)
#define PBLK 18            // pass2 chunks per partition (18*4096 >= PCAP)
#define OSTRIDE 392        // padded LDS out row stride (fp16)

typedef _Float16 f16x8 __attribute__((ext_vector_type(8)));
typedef float    f32x4 __attribute__((ext_vector_type(4)));

__device__ __forceinline__ unsigned short f2h(float f) {
    return __half_as_ushort(__float2half_rn(f));
}
__device__ __forceinline__ float2 h2f2(unsigned u) {
    __half2 h = *reinterpret_cast<__half2*>(&u);
    return __half22float2(h);
}
__device__ __forceinline__ float qdot2(const uint2& w, const float4& kd) {
    float2 a = h2f2(w.x);
    float2 b = h2f2(w.y);
    return a.x * kd.x + a.y * kd.y + b.x * kd.z + b.y * kd.w;
}
__device__ __forceinline__ void vacc2(const uint2& w, float e, float4& acc) {
    float2 a = h2f2(w.x);
    float2 b = h2f2(w.y);
    acc.x = fmaf(e, a.x, acc.x);
    acc.y = fmaf(e, a.y, acc.y);
    acc.z = fmaf(e, b.x, acc.z);
    acc.w = fmaf(e, b.y, acc.w);
}

// ---------------------------------------------------------------------------
// proj block body (shared by both fused kernels). smem must be >= 32*OSTRIDE*2
// bytes. Writes 32 rows starting at node row0.
// ---------------------------------------------------------------------------
__device__ __forceinline__ void proj_body(
    char* smem_raw, int tid, int row0,
    const float* __restrict__ h, const unsigned short* __restrict__ Wt,
    unsigned short* __restrict__ K, unsigned short* __restrict__ Qa,
    unsigned short* __restrict__ Va, int n)
{
    unsigned short* hsm = (unsigned short*)smem_raw;   // first 8KB: h tile fp16

    for (int idx = tid; idx < 32 * 32; idx += 256) {
        int r  = idx >> 5;
        int c4 = idx & 31;            // float4 column
        int gr = row0 + r;
        float4 hv = (gr < n) ? ((const float4*)h)[(size_t)gr * 32 + c4]
                             : make_float4(0.f, 0.f, 0.f, 0.f);
        int sc = (c4 * 4) ^ ((r & 7) << 3);
        __half2 p01 = __floats2half2_rn(hv.x, hv.y);
        __half2 p23 = __floats2half2_rn(hv.z, hv.w);
        uint2 u;
        u.x = *(unsigned*)&p01;
        u.y = *(unsigned*)&p23;
        *(uint2*)&hsm[r * IN_DIM + sc] = u;
    }
    __syncthreads();

    const int w = tid >> 6;
    const int l = tid & 63;
    const int l15 = l & 15;
    const int kg  = l >> 4;
    const _Float16* Wt16 = (const _Float16*)Wt;

    f32x4 acc[2][6];
#pragma unroll
    for (int rt = 0; rt < 2; ++rt)
#pragma unroll
        for (int ct = 0; ct < 6; ++ct) acc[rt][ct] = (f32x4){0.f, 0.f, 0.f, 0.f};

#pragma unroll
    for (int s = 0; s < 4; ++s) {
        int scol = (s * 32 + kg * 8) ^ ((l & 7) << 3);
        f16x8 a0 = *(const f16x8*)&hsm[l15 * IN_DIM + scol];
        f16x8 a1 = *(const f16x8*)&hsm[(l15 + 16) * IN_DIM + scol];
#pragma unroll
        for (int ct = 0; ct < 6; ++ct) {
            int c = w * 96 + ct * 16 + l15;
            f16x8 b = *(const f16x8*)&Wt16[(size_t)c * IN_DIM + s * 32 + kg * 8];
            acc[0][ct] = __builtin_amdgcn_mfma_f32_16x16x32_f16(a0, b, acc[0][ct], 0, 0, 0);
            acc[1][ct] = __builtin_amdgcn_mfma_f32_16x16x32_f16(a1, b, acc[1][ct], 0, 0, 0);
        }
    }
    __syncthreads();   // all hsm reads done; reuse LDS for out staging

    unsigned short* osm = (unsigned short*)smem_raw;   // 32 x OSTRIDE fp16
#pragma unroll
    for (int rt = 0; rt < 2; ++rt) {
#pragma unroll
        for (int ct = 0; ct < 6; ++ct) {
            int cD = w * 96 + ct * 16 + l15;
#pragma unroll
            for (int r = 0; r < 4; ++r) {
                int rowl = rt * 16 + kg * 4 + r;
                osm[rowl * OSTRIDE + cD] = f2h(acc[rt][ct][r]);
            }
        }
    }
    __syncthreads();

    for (int c = tid; c < 32 * 96; c += 256) {
        int row  = c / 96;
        int col4 = c - row * 96;
        int node = row0 + row;
        if (node >= n) continue;
        uint2 v = *(const uint2*)&osm[row * OSTRIDE + col4 * 4];
        int colbase = col4 * 4;
        if (colbase < 128)
            *(uint2*)&K [(size_t)node * OUTC + colbase] = v;
        else if (colbase < 256)
            *(uint2*)&Qa[(size_t)node * OUTC + (colbase - 128)] = v;
        else
            *(uint2*)&Va[(size_t)node * OUTC + (colbase - 256)] = v;
    }
}

// ---------------------------------------------------------------------------
// K0: W prep (fp16 B^T layout) + zero gcount/pcount (R12-verified).
// ---------------------------------------------------------------------------
__global__ __launch_bounds__(256) void w_prep(
    const float* __restrict__ Wq, const float* __restrict__ Wk,
    const float* __restrict__ Wv, unsigned short* __restrict__ Wt,
    int* __restrict__ gcount, int* __restrict__ pcount)
{
    int idx = blockIdx.x * 256 + threadIdx.x;
    if (idx < NBMAX) gcount[idx] = 0;
    if (idx >= NBMAX && idx < NBMAX + NP) pcount[idx - NBMAX] = 0;
    if (idx >= NCOLS * IN_DIM) return;
    int c = idx >> 7, k = idx & 127;
    int sel = c >> 7;              // 0:K 1:Q 2:V
    int cc  = c & 127;
    int head = cc >> 5, dcol = cc & 31;
    const float* W = (sel == 0) ? Wk : (sel == 1) ? Wq : Wv;
    Wt[idx] = f2h(W[(size_t)head * IN_DIM * HID + (size_t)k * HID + dcol]);
}

// ---------------------------------------------------------------------------
// D2: FUSED {pass1-partition || proj rows [0, projA*32)}.
// pass1: R12-verified block-wide hist, dst>>11, record src<<16|dst.
// ---------------------------------------------------------------------------
__global__ __launch_bounds__(256) void part_projA(
    const int* __restrict__ src, const int* __restrict__ dst,
    int* __restrict__ pcount, unsigned* __restrict__ ppairs,
    const float* __restrict__ h, const unsigned short* __restrict__ Wt,
    unsigned short* __restrict__ K, unsigned short* __restrict__ Qa,
    unsigned short* __restrict__ Va,
    int ne, int binblk, int n)
{
    __shared__ __align__(16) char smem_raw[32 * OSTRIDE * 2];   // 24.5KB
    const int tid = threadIdx.x;

    if ((int)blockIdx.x < binblk) {
        int* hist = (int*)smem_raw;
        int* base = hist + 32;
        const int bblk = blockIdx.x;

        if (tid < 32) hist[tid] = 0;
        __syncthreads();

        const int ne4 = ne >> 2;
        const int4* s4 = (const int4*)src;
        const int4* d4 = (const int4*)dst;

        int4 sv[4], dv[4];
        int loc[16], pk[16];
        bool val[4];
#pragma unroll
        for (int k2 = 0; k2 < 4; ++k2) {
            int idx = bblk * 1024 + k2 * 256 + tid;
            val[k2] = idx < ne4;
            if (val[k2]) { sv[k2] = s4[idx]; dv[k2] = d4[idx]; }
            else { sv[k2] = make_int4(0,0,0,0); dv[k2] = make_int4(0,0,0,0); }
        }
#pragma unroll
        for (int k2 = 0; k2 < 4; ++k2) {
            int dd[4] = { dv[k2].x, dv[k2].y, dv[k2].z, dv[k2].w };
#pragma unroll
            for (int j = 0; j < 4; ++j) {
                int p = dd[j] >> PSH;
                pk[k2*4+j]  = p;
                loc[k2*4+j] = val[k2] ? atomicAdd(&hist[p], 1) : 0;
            }
        }
        __syncthreads();
        if (tid < 32) base[tid] = hist[tid] ? atomicAdd(&pcount[tid], hist[tid]) : 0;
        __syncthreads();
#pragma unroll
        for (int k2 = 0; k2 < 4; ++k2) {
            if (!val[k2]) continue;
            int ss[4] = { sv[k2].x, sv[k2].y, sv[k2].z, sv[k2].w };
            int dd[4] = { dv[k2].x, dv[k2].y, dv[k2].z, dv[k2].w };
#pragma unroll
            for (int j = 0; j < 4; ++j) {
                int p   = pk[k2*4+j];
                int pos = base[p] + loc[k2*4+j];
                if (pos < PCAP)
                    ppairs[(size_t)p * PCAP + pos] =
                        ((unsigned)ss[j] << 16) | (unsigned)dd[j];
            }
        }
        if (bblk == 0 && tid == 0) {
            for (int e = ne4 * 4; e < ne; ++e) {
                int p   = dst[e] >> PSH;
                int pos = atomicAdd(&pcount[p], 1);
                if (pos < PCAP)
                    ppairs[(size_t)p * PCAP + pos] =
                        ((unsigned)src[e] << 16) | (unsigned)dst[e];
            }
        }
        return;
    }

    proj_body(smem_raw, tid, (blockIdx.x - binblk) * 32, h, Wt, K, Qa, Va, n);
}

// ---------------------------------------------------------------------------
// D3: FUSED {pass2 || proj rows [rowbase, n)}.
// pass2: R12-verified, bins partition chunks into 128 buckets each.
// ---------------------------------------------------------------------------
__global__ __launch_bounds__(256) void pass2_projB(
    const unsigned* __restrict__ ppairs, const int* __restrict__ pcount,
    int* __restrict__ gcount, unsigned* __restrict__ pairs,
    const float* __restrict__ h, const unsigned short* __restrict__ Wt,
    unsigned short* __restrict__ K, unsigned short* __restrict__ Qa,
    unsigned short* __restrict__ Va,
    int p2blk, int rowbase, int n)
{
    __shared__ __align__(16) char smem_raw[32 * OSTRIDE * 2];   // 24.5KB
    const int tid = threadIdx.x;

    if ((int)blockIdx.x < p2blk) {
        int* hist = (int*)smem_raw;
        int* base = hist + 128;
        const int p = blockIdx.x / PBLK;
        const int c = blockIdx.x % PBLK;

        int mp = pcount[p]; if (mp > PCAP) mp = PCAP;
        const int i0 = c * 4096;
        if (i0 >= mp) return;
        const int iend = min(i0 + 4096, mp);

        if (tid < 128) hist[tid] = 0;
        __syncthreads();

        const unsigned* pp = ppairs + (size_t)p * PCAP;
        unsigned rec[16];
        int loc[16], lb[16];
#pragma unroll
        for (int k = 0; k < 16; ++k) {
            int i = i0 + k * 256 + tid;
            if (i < iend) {
                unsigned r = pp[i];
                rec[k] = r;
                int b = ((r & 0xFFFFu) >> BSH) & 127;
                lb[k]  = b;
                loc[k] = atomicAdd(&hist[b], 1);
            } else {
                rec[k] = 0; lb[k] = -1; loc[k] = 0;
            }
        }
        __syncthreads();
        if (tid < 128)
            base[tid] = hist[tid] ? atomicAdd(&gcount[p * 128 + tid], hist[tid]) : 0;
        __syncthreads();
#pragma unroll
        for (int k = 0; k < 16; ++k) {
            if (lb[k] < 0) continue;
            unsigned r = rec[k];
            int gb  = p * 128 + lb[k];
            int pos = base[lb[k]] + loc[k];
            if (pos < BCAP)
                pairs[(size_t)gb * BCAP + pos] =
                    ((r >> 16) << BSH) | (r & (BN - 1));
        }
        return;
    }

    proj_body(smem_raw, tid, (blockIdx.x - p2blk) * 32 + rowbase,
              h, Wt, K, Qa, Va, n);
}

// ---------------------------------------------------------------------------
// K_C: bucket gather, two-phase (byte-identical to round 12, verified 110us).
// ---------------------------------------------------------------------------
__global__ __launch_bounds__(256) void gat_bucket(
    const unsigned* __restrict__ pairs, const int* __restrict__ gcount,
    const uint2* __restrict__ Q2, const uint2* __restrict__ V2,
    const ushort4* __restrict__ K4,
    float* __restrict__ out, int n, int nbuck)
{
    __shared__ unsigned short sl[BCAP];
    __shared__ float exls[BCAP * 4];        // per-head ex, 12KB
    __shared__ int cl[BN], cur[BN], off[BN + 1];

    const int b = blockIdx.x;
    if (b >= nbuck) return;
    const int tid = threadIdx.x;

    if (tid < BN) cl[tid] = 0;
    __syncthreads();

    int m = gcount[b]; if (m > BCAP) m = BCAP;
    const unsigned* pb = pairs + (size_t)b * BCAP;

    for (int i = tid; i < m; i += 256) atomicAdd(&cl[pb[i] & (BN - 1)], 1);
    __syncthreads();
    if (tid == 0) {
        int a = 0;
#pragma unroll
        for (int i = 0; i < BN; ++i) { off[i] = a; cur[i] = a; a += cl[i]; }
        off[BN] = a;
    }
    __syncthreads();
    for (int i = tid; i < m; i += 256) {
        unsigned p = pb[i];
        int pos = atomicAdd(&cur[p & (BN - 1)], 1);
        sl[pos] = (unsigned short)(p >> BSH);
    }
    __syncthreads();

    const int gi   = tid >> 5;       // group 0..7 (one node per group per q)
    const int l32  = tid & 31;
    const int hsel = l32 >> 3;       // head 0..3
    const bool wr  = (l32 & 7) == 0; // one writer lane per head

    float dsum[BN / 8];

    // ---- phase A: scores ----
#pragma unroll
    for (int q = 0; q < BN / 8; ++q) {
        int nl   = q * 8 + gi;
        int node = b * BN + nl;
        float ds = 0.f;
        if (node < n) {
            ushort4 kh = K4[(size_t)node * 32 + l32];
            float2 k01 = h2f2(*(unsigned*)&kh.x);
            float2 k23 = h2f2(*(unsigned*)&kh.z);
            const float4 kd = make_float4(k01.x, k01.y, k23.x, k23.y);

            int j        = off[nl];
            const int je = off[nl + 1];
            for (; j + 3 < je; j += 4) {
                int s0 = sl[j], s1 = sl[j + 1], s2 = sl[j + 2], s3 = sl[j + 3];
                uint2 w0 = Q2[(size_t)s0 * 32 + l32];
                uint2 w1 = Q2[(size_t)s1 * 32 + l32];
                uint2 w2 = Q2[(size_t)s2 * 32 + l32];
                uint2 w3 = Q2[(size_t)s3 * 32 + l32];
                float p0 = qdot2(w0, kd), p1 = qdot2(w1, kd);
                float p2 = qdot2(w2, kd), p3 = qdot2(w3, kd);
#pragma unroll
                for (int o = 1; o < 8; o <<= 1) {
                    p0 += __shfl_xor(p0, o, 8);
                    p1 += __shfl_xor(p1, o, 8);
                    p2 += __shfl_xor(p2, o, 8);
                    p3 += __shfl_xor(p3, o, 8);
                }
                float e0 = __expf(p0 > 0.f ? p0 : NEG_SLOPE * p0);
                float e1 = __expf(p1 > 0.f ? p1 : NEG_SLOPE * p1);
                float e2 = __expf(p2 > 0.f ? p2 : NEG_SLOPE * p2);
                float e3 = __expf(p3 > 0.f ? p3 : NEG_SLOPE * p3);
                ds += (e0 + e1) + (e2 + e3);
                if (wr) {
                    exls[(j    ) * 4 + hsel] = e0;
                    exls[(j + 1) * 4 + hsel] = e1;
                    exls[(j + 2) * 4 + hsel] = e2;
                    exls[(j + 3) * 4 + hsel] = e3;
                }
            }
            for (; j < je; ++j) {
                int s0 = sl[j];
                uint2 w0 = Q2[(size_t)s0 * 32 + l32];
                float p0 = qdot2(w0, kd);
#pragma unroll
                for (int o = 1; o < 8; o <<= 1) p0 += __shfl_xor(p0, o, 8);
                float e0 = __expf(p0 > 0.f ? p0 : NEG_SLOPE * p0);
                ds += e0;
                if (wr) exls[j * 4 + hsel] = e0;
            }
        }
        dsum[q] = ds;
    }
    __syncthreads();

    // ---- phase B: values ----
#pragma unroll
    for (int q = 0; q < BN / 8; ++q) {
        int nl   = q * 8 + gi;
        int node = b * BN + nl;
        if (node >= n) continue;

        int j        = off[nl];
        const int je = off[nl + 1];
        float4 acc = make_float4(0.f, 0.f, 0.f, 0.f);

        for (; j + 3 < je; j += 4) {
            int s0 = sl[j], s1 = sl[j + 1], s2 = sl[j + 2], s3 = sl[j + 3];
            uint2 w0 = V2[(size_t)s0 * 32 + l32];
            uint2 w1 = V2[(size_t)s1 * 32 + l32];
            uint2 w2 = V2[(size_t)s2 * 32 + l32];
            uint2 w3 = V2[(size_t)s3 * 32 + l32];
            float e0 = exls[(j    ) * 4 + hsel];
            float e1 = exls[(j + 1) * 4 + hsel];
            float e2 = exls[(j + 2) * 4 + hsel];
            float e3 = exls[(j + 3) * 4 + hsel];
            vacc2(w0, e0, acc); vacc2(w1, e1, acc);
            vacc2(w2, e2, acc); vacc2(w3, e3, acc);
        }
        for (; j < je; ++j) {
            int s0 = sl[j];
            uint2 w0 = V2[(size_t)s0 * 32 + l32];
            float e0 = exls[j * 4 + hsel];
            vacc2(w0, e0, acc);
        }

        float inv = 1.f / fmaxf(dsum[q], 1e-9f);
        float4 o; o.x = acc.x*inv; o.y = acc.y*inv; o.z = acc.z*inv; o.w = acc.w*inv;
        ((float4*)out)[(size_t)node * 32 + l32] = o;
    }
}

extern "C" void kernel_launch(void* const* d_in, const int* in_sizes, int n_in,
                              void* d_out, int out_size, void* d_ws, size_t ws_size,
                              hipStream_t stream) {
    const float* h   = (const float*)d_in[0];
    const int*   src = (const int*)d_in[1];
    const int*   dst = (const int*)d_in[2];
    const float* Wq  = (const float*)d_in[3];
    const float* Wk  = (const float*)d_in[4];
    const float* Wv  = (const float*)d_in[5];
    float* out = (float*)d_out;

    const int n     = in_sizes[0] / IN_DIM;   // 50000
    const int ne    = in_sizes[1];            // 1.6M
    const int nbuck = (n + BN - 1) >> BSH;    // 3125

    // workspace: K|Qa|Va f16 | gcount | pcount | ppairs | pairs | Wt (~56 MB)
    unsigned short* K      = (unsigned short*)d_ws;
    unsigned short* Qa     = K  + (size_t)n * OUTC;
    unsigned short* Va     = Qa + (size_t)n * OUTC;
    int*            gcount = (int*)(Va + (size_t)n * OUTC);
    int*            pcount = gcount + NBMAX;
    unsigned*       ppairs = (unsigned*)(pcount + 64);
    unsigned*       pairs  = ppairs + (size_t)NP * PCAP;
    unsigned short* Wt     = (unsigned short*)(pairs + (size_t)NBMAX * BCAP);

    w_prep<<<WPB, 256, 0, stream>>>(Wq, Wk, Wv, Wt, gcount, pcount);

    int ne4     = ne >> 2;
    int binblk  = (ne4 + 1023) / 1024;        // 391
    int projblk = (n + 31) / 32;              // 1563
    int projA   = (projblk + 1) / 2;          // 782 (rows 0..25024)
    int projB   = projblk - projA;            // 781

    part_projA<<<binblk + projA, 256, 0, stream>>>(
        src, dst, pcount, ppairs, h, Wt, K, Qa, Va, ne, binblk, n);

    int p2blk = NP * PBLK;                    // 450
    pass2_projB<<<p2blk + projB, 256, 0, stream>>>(
        ppairs, pcount, gcount, pairs, h, Wt, K, Qa, Va,
        p2blk, projA * 32, n);

    gat_bucket<<<nbuck, 256, 0, stream>>>(pairs, gcount, (const uint2*)Qa,
                                          (const uint2*)Va, (const ushort4*)K,
                                          out, n, nbuck);
}